// Round 9
// baseline (195.698 us; speedup 1.0000x reference)
//
#include <hip/hip_runtime.h>

// (B,P,C,H,W)=(256,10,32,8,8); Tm=19, Ta=10, hw=64. All I/O fp32.
// Horner: A_0=[F_0;1]; A_{p+1}=A_p*M_p+[F_{p+1};1] (p=0..8) -> A_9=[G;W]
// out[b,t,c,j] = (G[c,:].M_t[:,j]) / (W.M_t[:,j] + eps)
//
// v9 = v8 + software-pipelined M in REGISTERS: lane j holds M_p[:,j] in a
// 64-reg array (static indices, fully unrolled k-loops); M_{p+1} streams into
// a second array during compute (64 independent loads fully hidden behind
// ~1300 cyc of VALU). Phase 1: no LDS, no barriers. Weight row only on wave 7.

#define EPSV 1e-6f

__device__ __forceinline__ float rdlane(float v, int k) {
    return __int_as_float(__builtin_amdgcn_readlane(__float_as_int(v), k));
}

// G^T layout: element G[r][k] at k*40 + (r ^ swz(k)), swz = ((k>>2)&1)<<2.
// Quads (r0%4==0) stay contiguous & 16B-aligned; W row at r=32 (32^4=36<40).
__device__ __forceinline__ int at_off(int k, int r) {
    return k * 40 + (r ^ (((k >> 2) & 1) << 2));
}

__global__ __launch_bounds__(512, 1) void k_fused(
    const float* __restrict__ feats,   // (256,10,32,64)
    const float* __restrict__ sim,     // (256,19,64,64)
    float* __restrict__ out)           // (2560,32,64)
{
    __shared__ __attribute__((aligned(16))) float At[2560];   // [G;W]^T, 10 KB

    const int tid  = threadIdx.x;
    const int lane = tid & 63;
    const int wave = tid >> 6;          // 0..7
    const int b    = blockIdx.x;

    const float* fb = feats + (size_t)b * 20480;   // 10*32*64
    const float* sb = sim   + (size_t)b * 77824;   // 19*64*64

    // ---- phase 1: A rows + M column in registers; no LDS, no barriers ----
    const int r0 = wave * 4;
    float a0 = fb[(r0 + 0) * 64 + lane];
    float a1 = fb[(r0 + 1) * 64 + lane];
    float a2 = fb[(r0 + 2) * 64 + lane];
    float a3 = fb[(r0 + 3) * 64 + lane];
    float aw = 1.0f;                    // weight row: only wave 7's copy is used

    float mc[64];                       // M_p column `lane` (static-index regs)
    #pragma unroll
    for (int k = 0; k < 64; ++k) mc[k] = sb[k * 64 + lane];

    for (int p = 0; p < 9; ++p) {
        float mn[64];                   // prefetch M_{p+1} column (independent)
        if (p < 8) {
            const float* __restrict__ Mn = sb + (p + 1) * 4096;
            #pragma unroll
            for (int k = 0; k < 64; ++k) mn[k] = Mn[k * 64 + lane];
        }
        const float* __restrict__ F = fb + (p + 1) * 2048;
        const float f0 = F[(r0 + 0) * 64 + lane];
        const float f1 = F[(r0 + 1) * 64 + lane];
        const float f2 = F[(r0 + 2) * 64 + lane];
        const float f3 = F[(r0 + 3) * 64 + lane];

        float c0 = 0.f, c1 = 0.f, c2 = 0.f, c3 = 0.f, cw = 0.f;
        if (wave == 7) {                // wave-uniform split: 5-row vs 4-row body
            #pragma unroll
            for (int k = 0; k < 64; ++k) {
                const float m = mc[k];
                c0 += rdlane(a0, k) * m;
                c1 += rdlane(a1, k) * m;
                c2 += rdlane(a2, k) * m;
                c3 += rdlane(a3, k) * m;
                cw += rdlane(aw, k) * m;
            }
        } else {
            #pragma unroll
            for (int k = 0; k < 64; ++k) {
                const float m = mc[k];
                c0 += rdlane(a0, k) * m;
                c1 += rdlane(a1, k) * m;
                c2 += rdlane(a2, k) * m;
                c3 += rdlane(a3, k) * m;
            }
        }
        a0 = c0 + f0; a1 = c1 + f1; a2 = c2 + f2; a3 = c3 + f3; aw = cw + 1.0f;

        if (p < 8) {                    // rotate prefetch buffer (64 v_mov)
            #pragma unroll
            for (int k = 0; k < 64; ++k) mc[k] = mn[k];
        }
    }

    // ---- handoff: [G;W]^T -> LDS ----
    At[at_off(lane, r0 + 0)] = a0;
    At[at_off(lane, r0 + 1)] = a1;
    At[at_off(lane, r0 + 2)] = a2;
    At[at_off(lane, r0 + 3)] = a3;
    if (wave == 7) At[at_off(lane, 32)] = aw;
    __syncthreads();                    // the kernel's only barrier

    // ---- phase 2: one wave per t (8x4 lane tiles), M from global, no barriers ----
    const int rr = (lane >> 4) * 8;     // 0,8,16,24
    const int jj = (lane & 15) * 4;
    const int njobs = (wave < 2) ? 2 : 1;

    for (int rep = 0; rep < njobs; ++rep) {
        const int t = wave + rep * 8;
        const float* __restrict__ Mt = sb + (9 + t) * 4096;

        float acc[32];
        #pragma unroll
        for (int i = 0; i < 32; ++i) acc[i] = 0.f;
        float wv0 = 0.f, wv1 = 0.f, wv2 = 0.f, wv3 = 0.f;

        #pragma unroll 16
        for (int k = 0; k < 64; ++k) {
            const float4 g0 = *(const float4*)&At[at_off(k, rr)];      // rows rr..+3
            const float4 g1 = *(const float4*)&At[at_off(k, rr + 4)];  // rows rr+4..+7
            const float  wk = At[at_off(k, 32)];                       // W[k], broadcast
            const float4 m  = *(const float4*)&Mt[k * 64 + jj];        // global b128
            wv0 += wk * m.x; wv1 += wk * m.y; wv2 += wk * m.z; wv3 += wk * m.w;
            acc[0]  += g0.x*m.x; acc[1]  += g0.x*m.y; acc[2]  += g0.x*m.z; acc[3]  += g0.x*m.w;
            acc[4]  += g0.y*m.x; acc[5]  += g0.y*m.y; acc[6]  += g0.y*m.z; acc[7]  += g0.y*m.w;
            acc[8]  += g0.z*m.x; acc[9]  += g0.z*m.y; acc[10] += g0.z*m.z; acc[11] += g0.z*m.w;
            acc[12] += g0.w*m.x; acc[13] += g0.w*m.y; acc[14] += g0.w*m.z; acc[15] += g0.w*m.w;
            acc[16] += g1.x*m.x; acc[17] += g1.x*m.y; acc[18] += g1.x*m.z; acc[19] += g1.x*m.w;
            acc[20] += g1.y*m.x; acc[21] += g1.y*m.y; acc[22] += g1.y*m.z; acc[23] += g1.y*m.w;
            acc[24] += g1.z*m.x; acc[25] += g1.z*m.y; acc[26] += g1.z*m.z; acc[27] += g1.z*m.w;
            acc[28] += g1.w*m.x; acc[29] += g1.w*m.y; acc[30] += g1.w*m.z; acc[31] += g1.w*m.w;
        }

        float4 rw;
        rw.x = 1.f / (wv0 + EPSV); rw.y = 1.f / (wv1 + EPSV);
        rw.z = 1.f / (wv2 + EPSV); rw.w = 1.f / (wv3 + EPSV);

        float* ob = out + ((size_t)b * 10 + t) * 2048;
        #pragma unroll
        for (int i = 0; i < 8; ++i) {
            float4 o;
            o.x = acc[i * 4 + 0] * rw.x;
            o.y = acc[i * 4 + 1] * rw.y;
            o.z = acc[i * 4 + 2] * rw.z;
            o.w = acc[i * 4 + 3] * rw.w;
            *(float4*)&ob[(rr + i) * 64 + jj] = o;
        }
    }
}

extern "C" void kernel_launch(void* const* d_in, const int* in_sizes, int n_in,
                              void* d_out, int out_size, void* d_ws, size_t ws_size,
                              hipStream_t stream) {
    const float* feats = (const float*)d_in[0];
    const float* sim   = (const float*)d_in[1];
    k_fused<<<256, 512, 0, stream>>>(feats, sim, (float*)d_out);
}

// Round 10
// 167.082 us; speedup vs baseline: 1.1713x; 1.1713x over previous
//
#include <hip/hip_runtime.h>

// (B,P,C,H,W)=(256,10,32,8,8); Tm=19, Ta=10, hw=64. All I/O fp32.
// Horner: A_0=[F_0;1]; A_{p+1}=A_p*M_p+[F_{p+1};1] (p=0..8) -> A_9=[G;W]
// out[b,t,c,j] = (G[c,:].M_t[:,j]) / (W.M_t[:,j] + eps)
//
// v10: the recursion is ROW-INDEPENDENT -> split each batch into two
// 16-row half-blocks (grid 512 = 2 blocks/CU = 4 waves/SIMD: 4 independent
// latency chains per SIMD, the thing R5-R9 lacked). Phase 1: 2 rows/wave in
// registers, A[r,k] via v_readlane, M[k,lane] coalesced global b32; no LDS,
// no barriers. One barrier hands [G_half;W]^T to 5KB LDS. Phase 2: wave-per-t
// 4x4-row tiles on the owned half (10 jobs / 8 waves), barrier-free.

#define EPSV 1e-6f

__device__ __forceinline__ float rdlane(float v, int k) {
    return __int_as_float(__builtin_amdgcn_readlane(__float_as_int(v), k));
}

__global__ __launch_bounds__(512, 4) void k_fused(
    const float* __restrict__ feats,   // (256,10,32,64)
    const float* __restrict__ sim,     // (256,19,64,64)
    float* __restrict__ out)           // (2560,32,64)
{
    // Gt[k*20 + r'], r'=0..15 half G rows, r'=16 = W row. 5 KB.
    __shared__ __attribute__((aligned(16))) float Gt[1280];

    const int tid  = threadIdx.x;
    const int lane = tid & 63;
    const int wave = tid >> 6;          // 0..7
    const int b    = blockIdx.x >> 1;
    const int h    = blockIdx.x & 1;    // row-half of the batch

    const float* fb = feats + (size_t)b * 20480;   // 10*32*64
    const float* sb = sim   + (size_t)b * 77824;   // 19*64*64

    // ---- phase 1: wave owns rows r0,r0+1 (wave 7 also W). Registers only. ----
    const int r0 = 16 * h + 2 * wave;
    float a0 = fb[(r0 + 0) * 64 + lane];
    float a1 = fb[(r0 + 1) * 64 + lane];
    float aw = 1.0f;

    for (int p = 0; p < 9; ++p) {
        const float* __restrict__ M = sb + p * 4096;
        const float* __restrict__ F = fb + (p + 1) * 2048;
        const float f0 = F[(r0 + 0) * 64 + lane];
        const float f1 = F[(r0 + 1) * 64 + lane];

        float c0 = 0.f, c1 = 0.f, cw = 0.f;
        if (wave == 7) {                // wave-uniform branch
            #pragma unroll
            for (int k = 0; k < 64; ++k) {
                const float m = M[k * 64 + lane];   // coalesced 256B, L1/L2-hot
                c0 += rdlane(a0, k) * m;
                c1 += rdlane(a1, k) * m;
                cw += rdlane(aw, k) * m;
            }
        } else {
            #pragma unroll
            for (int k = 0; k < 64; ++k) {
                const float m = M[k * 64 + lane];
                c0 += rdlane(a0, k) * m;
                c1 += rdlane(a1, k) * m;
            }
        }
        a0 = c0 + f0; a1 = c1 + f1; aw = cw + 1.0f;
    }

    // ---- handoff: half G + W -> LDS (k = lane, transposed one-time writes) ----
    Gt[lane * 20 + 2 * wave + 0] = a0;
    Gt[lane * 20 + 2 * wave + 1] = a1;
    if (wave == 7) Gt[lane * 20 + 16] = aw;
    __syncthreads();                    // the kernel's only barrier

    // ---- phase 2: 10 jobs (t=0..9) over 8 waves; 16 rows x 64 cols per job ----
    const int rr = (lane >> 4) * 4;     // 0,4,8,12 (within the half)
    const int jj = (lane & 15) * 4;
    const int njobs = (wave < 2) ? 2 : 1;

    for (int rep = 0; rep < njobs; ++rep) {
        const int t = wave + rep * 8;
        const float* __restrict__ Mt = sb + (9 + t) * 4096;

        float acc[16];
        #pragma unroll
        for (int i = 0; i < 16; ++i) acc[i] = 0.f;
        float wv0 = 0.f, wv1 = 0.f, wv2 = 0.f, wv3 = 0.f;

        #pragma unroll 16
        for (int k = 0; k < 64; ++k) {
            const float4 g  = *(const float4*)&Gt[k * 20 + rr];   // 4 rows @ k
            const float  wk = Gt[k * 20 + 16];                    // W[k], broadcast
            const float4 m  = *(const float4*)&Mt[k * 64 + jj];   // global b128
            wv0 += wk * m.x; wv1 += wk * m.y; wv2 += wk * m.z; wv3 += wk * m.w;
            acc[0]  += g.x*m.x; acc[1]  += g.x*m.y; acc[2]  += g.x*m.z; acc[3]  += g.x*m.w;
            acc[4]  += g.y*m.x; acc[5]  += g.y*m.y; acc[6]  += g.y*m.z; acc[7]  += g.y*m.w;
            acc[8]  += g.z*m.x; acc[9]  += g.z*m.y; acc[10] += g.z*m.z; acc[11] += g.z*m.w;
            acc[12] += g.w*m.x; acc[13] += g.w*m.y; acc[14] += g.w*m.z; acc[15] += g.w*m.w;
        }

        float4 rw;
        rw.x = 1.f / (wv0 + EPSV); rw.y = 1.f / (wv1 + EPSV);
        rw.z = 1.f / (wv2 + EPSV); rw.w = 1.f / (wv3 + EPSV);

        float* ob = out + ((size_t)b * 10 + t) * 2048;
        #pragma unroll
        for (int i = 0; i < 4; ++i) {
            float4 o;
            o.x = acc[i * 4 + 0] * rw.x;
            o.y = acc[i * 4 + 1] * rw.y;
            o.z = acc[i * 4 + 2] * rw.z;
            o.w = acc[i * 4 + 3] * rw.w;
            *(float4*)&ob[(16 * h + rr + i) * 64 + jj] = o;
        }
    }
}

extern "C" void kernel_launch(void* const* d_in, const int* in_sizes, int n_in,
                              void* d_out, int out_size, void* d_ws, size_t ws_size,
                              hipStream_t stream) {
    const float* feats = (const float*)d_in[0];
    const float* sim   = (const float*)d_in[1];
    k_fused<<<512, 512, 0, stream>>>(feats, sim, (float*)d_out);
}